// Round 6
// baseline (214.063 us; speedup 1.0000x reference)
//
#include <hip/hip_runtime.h>

#define NPIX    65536
#define D       64
#define KCODES  1024
#define SPLIT   4
#define KCHUNK  (KCODES / SPLIT)   // 256
#define PIXB    64
#define BLOCK   256

// d_out layout (floats):
//   [0]                  loss
//   [1 .. 4194305)       quantized_out (NCHW, 16x64x64x64)
//   [4194305]            perplexity
//   [4194306 .. 71303170) encodings (65536 x 1024)
//   [71303170 .. 71368706) indices (as float)
#define QUANT_OFF 1
#define PERP_OFF  4194305
#define ENC_OFF   4194306u
#define IDX_OFF   71303170u

// numpy pairwise_sum (8 <= n <= 128) for n=64: 8 accumulators over stride-8
// lanes, sequential adds, then ((r0+r1)+(r2+r3))+((r4+r5)+(r6+r7)).
// All ops via __fmul_rn/__fadd_rn so the compiler cannot contract or reorder.

__global__ __launch_bounds__(256) void vq_init(const float* __restrict__ emb,
                                               double* __restrict__ loss_sum,
                                               int* __restrict__ counts,
                                               float* __restrict__ se) {
    int t = blockIdx.x * 256 + threadIdx.x;
    if (t == 0) *loss_sum = 0.0;
    if (t < KCODES) {
        counts[t] = 0;
        const float* e = emb + (size_t)t * D;
        float r[8];
        #pragma unroll
        for (int j = 0; j < 8; ++j) r[j] = __fmul_rn(e[j], e[j]);
        #pragma unroll
        for (int i = 8; i < D; i += 8)
            #pragma unroll
            for (int j = 0; j < 8; ++j)
                r[j] = __fadd_rn(r[j], __fmul_rn(e[i + j], e[i + j]));
        float X = __fadd_rn(__fadd_rn(r[0], r[1]), __fadd_rn(r[2], r[3]));
        float Y = __fadd_rn(__fadd_rn(r[4], r[5]), __fadd_rn(r[6], r[7]));
        se[t] = __fadd_rn(X, Y);
    }
}

// x tile lives in LDS (xs[d][pixel], conflict-free b32 reads), not registers:
// rounds 3-5 proved the allocator will not keep a 64-elem per-thread array
// resident (VGPR stuck at 48-56, x rematerialized from cache every k-iter,
// VALU-issue time ~2.2x the FMA floor).
__global__ __launch_bounds__(256) void vq_main(const float* __restrict__ in,
                                               const float* __restrict__ emb,
                                               const float* __restrict__ se,
                                               float* __restrict__ out,
                                               double* __restrict__ loss_sum,
                                               int* __restrict__ counts) {
    __shared__ float xs[D][PIXB];       // 16 KB
    __shared__ float sb[SPLIT][PIXB];
    __shared__ int   sk[SPLIT][PIXB];
    __shared__ int   skfin[PIXB];

    const int tid   = threadIdx.x;
    const int lane  = tid & 63;
    const int split = tid >> 6;
    const int n0    = blockIdx.x * PIXB;
    const int n     = n0 + lane;
    const int b     = n0 >> 12;         // batch (constant per block: 4096%64==0)
    const int s0    = n0 & 4095;

    // cooperative stage: 64 pixels x 64 dims, coalesced (wave reads 64
    // consecutive floats per d), conflict-free LDS writes (consecutive dwords)
    {
        const float* base = in + ((size_t)b << 18) + s0;
        #pragma unroll
        for (int i = 0; i < 16; ++i) {
            int d = split + (i << 2);
            xs[d][lane] = base[((size_t)d << 12) + lane];
        }
    }
    __syncthreads();

    // s_x exactly as numpy's pairwise_sum(flat*flat) for n=64
    float sx;
    {
        float r[8];
        #pragma unroll
        for (int j = 0; j < 8; ++j) {
            float v = xs[j][lane];
            r[j] = __fmul_rn(v, v);
        }
        #pragma unroll
        for (int i = 8; i < D; i += 8)
            #pragma unroll
            for (int j = 0; j < 8; ++j) {
                float v = xs[i + j][lane];
                r[j] = __fadd_rn(r[j], __fmul_rn(v, v));
            }
        float X = __fadd_rn(__fadd_rn(r[0], r[1]), __fadd_rn(r[2], r[3]));
        float Y = __fadd_rn(__fadd_rn(r[4], r[5]), __fadd_rn(r[6], r[7]));
        sx = __fadd_rn(X, Y);
    }

    // wave-uniform codebook chunk base -> scalar (s_load) codebook reads
    const int kbase = __builtin_amdgcn_readfirstlane(split * KCHUNK);
    const float* eb = emb + (size_t)kbase * D;
    const float* hb = se + kbase;

    float best = 3.0e38f;
    int bestk  = 0x7fffffff;
    int lane_off = lane;

    for (int k = 0; k < KCHUNK; k += 4) {
        // redefine lane_off each iteration so LICM cannot hoist the 64
        // xs reads out of the k-loop (would recreate 64 live VGPRs)
        asm volatile("" : "+v"(lane_off));
        const float* e0 = eb + (size_t)(k + 0) * D;
        const float* e1 = eb + (size_t)(k + 1) * D;
        const float* e2 = eb + (size_t)(k + 2) * D;
        const float* e3 = eb + (size_t)(k + 3) * D;
        // sgemm-style dot: single sequential fused-FMA chain over d, per code
        float a0 = 0.f, a1 = 0.f, a2 = 0.f, a3 = 0.f;
        #pragma unroll
        for (int d = 0; d < D; ++d) {
            float xd = xs[d][lane_off];
            a0 = fmaf(xd, e0[d], a0);
            a1 = fmaf(xd, e1[d], a1);
            a2 = fmaf(xd, e2[d], a2);
            a3 = fmaf(xd, e3[d], a3);
        }
        // numpy: fl( fl(sx + se_k) - 2*m_k ), evaluated (A+B) - 2.0*M
        float s0v = __fsub_rn(__fadd_rn(sx, hb[k + 0]), __fmul_rn(2.0f, a0));
        float s1v = __fsub_rn(__fadd_rn(sx, hb[k + 1]), __fmul_rn(2.0f, a1));
        float s2v = __fsub_rn(__fadd_rn(sx, hb[k + 2]), __fmul_rn(2.0f, a2));
        float s3v = __fsub_rn(__fadd_rn(sx, hb[k + 3]), __fmul_rn(2.0f, a3));
        // strict < in ascending k == np.argmin first-min semantics
        if (s0v < best) { best = s0v; bestk = kbase + k + 0; }
        if (s1v < best) { best = s1v; bestk = kbase + k + 1; }
        if (s2v < best) { best = s2v; bestk = kbase + k + 2; }
        if (s3v < best) { best = s3v; bestk = kbase + k + 3; }
    }

    sb[split][lane] = best;
    sk[split][lane] = bestk;
    __syncthreads();

    if (split == 0) {
        // ascending split order + strict < preserves np.argmin first-min
        #pragma unroll
        for (int j = 1; j < SPLIT; ++j) {
            float bj = sb[j][lane];
            int   kj = sk[j][lane];
            if (bj < best) { best = bj; bestk = kj; }
        }
        skfin[lane] = bestk;
        atomicAdd(&counts[bestk], 1);
        out[IDX_OFF + (unsigned)n] = (float)bestk;

        // quantized (NCHW) + per-pixel squared error
        const float* eq = emb + (size_t)bestk * D;
        float* qout = out + QUANT_OFF + ((size_t)b << 18) + s0 + lane;
        float mse = 0.f;
        #pragma unroll
        for (int d = 0; d < D; ++d) {
            float q = eq[d];
            qout[(size_t)d << 12] = q;
            float df = q - xs[d][lane];
            mse = fmaf(df, df, mse);
        }
        #pragma unroll
        for (int off = 32; off; off >>= 1) mse += __shfl_down(mse, off);
        if (lane == 0) atomicAdd(loss_sum, (double)mse);
    }
    __syncthreads();

    // one-hot encodings rows for this block's 64 pixels (256 KB).
    // Region starts at ENC_OFF + n0*1024 (global float idx == 2 mod 4), so
    // shift by 2 floats for aligned float4 stores; head/tail as float2.
    float4* dst4 = (float4*)(out + ENC_OFF + (size_t)n0 * KCODES + 2);
    for (int i = tid; i < 16383; i += BLOCK) {
        int flat = (i << 2) + 2;          // 2 .. 65530
        int r0 = flat >> 10;
        int r1 = (flat + 3) >> 10;        // row crossing only at c==1022
        int k0 = skfin[r0];
        int k1 = skfin[r1];
        int c  = flat & 1023;             // in {2,6,...,1022}
        float4 v;
        v.x = (c == k0) ? 1.f : 0.f;
        v.y = (c + 1 == k0) ? 1.f : 0.f;
        v.z = (((flat + 2) & 1023) == k1) ? 1.f : 0.f;
        v.w = (((flat + 3) & 1023) == k1) ? 1.f : 0.f;
        dst4[i] = v;
    }
    if (tid == 0) {
        float2* dh = (float2*)(out + ENC_OFF + (size_t)n0 * KCODES);
        int kh = skfin[0];
        float2 h2; h2.x = (kh == 0) ? 1.f : 0.f; h2.y = (kh == 1) ? 1.f : 0.f;
        *dh = h2;
        float2* dt = (float2*)(out + ENC_OFF + (size_t)n0 * KCODES + 65534);
        int kt = skfin[63];
        float2 t2; t2.x = (kt == 1022) ? 1.f : 0.f; t2.y = (kt == 1023) ? 1.f : 0.f;
        *dt = t2;
    }
}

__global__ __launch_bounds__(256) void vq_fin(const double* __restrict__ loss_sum,
                                              const int* __restrict__ counts,
                                              float* __restrict__ out) {
    __shared__ double red[256];
    int t = threadIdx.x;
    double ent = 0.0;
    for (int k = t; k < KCODES; k += 256) {
        double p = (double)counts[k] / 65536.0;
        ent -= p * log(p + 1e-10);
    }
    red[t] = ent;
    __syncthreads();
    for (int o = 128; o; o >>= 1) {
        if (t < o) red[t] += red[t + o];
        __syncthreads();
    }
    if (t == 0) {
        out[PERP_OFF] = (float)exp(red[0]);
        out[0] = (float)(1.25 * (*loss_sum) / 4194304.0);
    }
}

extern "C" void kernel_launch(void* const* d_in, const int* in_sizes, int n_in,
                              void* d_out, int out_size, void* d_ws, size_t ws_size,
                              hipStream_t stream) {
    const float* in  = (const float*)d_in[0];
    const float* emb = (const float*)d_in[1];
    float* out = (float*)d_out;

    double* loss_sum = (double*)d_ws;
    int*    counts   = (int*)((char*)d_ws + 8);
    float*  se       = (float*)((char*)d_ws + 8 + 4096);

    vq_init<<<4, 256, 0, stream>>>(emb, loss_sum, counts, se);
    vq_main<<<NPIX / PIXB, BLOCK, 0, stream>>>(in, emb, se, out, loss_sum, counts);
    vq_fin<<<1, 256, 0, stream>>>(loss_sum, counts, out);
}

// Round 7
// 203.108 us; speedup vs baseline: 1.0539x; 1.0539x over previous
//
#include <hip/hip_runtime.h>

#define NPIX    65536
#define D       64
#define KCODES  1024
#define SPLIT   4
#define KCHUNK  (KCODES / SPLIT)   // 256
#define PIXB    64
#define BLOCK   256
#define XPAD    68                 // row stride in floats: (4p+d)%32 spreads banks

// d_out layout (floats):
//   [0]                  loss
//   [1 .. 4194305)       quantized_out (NCHW, 16x64x64x64)
//   [4194305]            perplexity
//   [4194306 .. 71303170) encodings (65536 x 1024)
//   [71303170 .. 71368706) indices (as float)
#define QUANT_OFF 1
#define PERP_OFF  4194305
#define ENC_OFF   4194306u
#define IDX_OFF   71303170u

// numpy pairwise_sum (8 <= n <= 128) for n=64: 8 accumulators over stride-8
// lanes, sequential adds, then ((r0+r1)+(r2+r3))+((r4+r5)+(r6+r7)).
// All ops via __fmul_rn/__fadd_rn so the compiler cannot contract or reorder.

__global__ __launch_bounds__(256) void vq_init(const float* __restrict__ emb,
                                               double* __restrict__ loss_sum,
                                               int* __restrict__ counts,
                                               float* __restrict__ se) {
    int t = blockIdx.x * 256 + threadIdx.x;
    if (t == 0) *loss_sum = 0.0;
    if (t < KCODES) {
        counts[t] = 0;
        const float* e = emb + (size_t)t * D;
        float r[8];
        #pragma unroll
        for (int j = 0; j < 8; ++j) r[j] = __fmul_rn(e[j], e[j]);
        #pragma unroll
        for (int i = 8; i < D; i += 8)
            #pragma unroll
            for (int j = 0; j < 8; ++j)
                r[j] = __fadd_rn(r[j], __fmul_rn(e[i + j], e[i + j]));
        float X = __fadd_rn(__fadd_rn(r[0], r[1]), __fadd_rn(r[2], r[3]));
        float Y = __fadd_rn(__fadd_rn(r[4], r[5]), __fadd_rn(r[6], r[7]));
        se[t] = __fadd_rn(X, Y);
    }
}

// Round-6 was LDS-pipe-bound (64 b32 reads / 4-code group = 158 us of LDS).
// Now: xs[pixel][d] padded rows, lane reads its own row as ds_read_b128 with
// constant offsets, 8 codes per group -> 16 b128 reads per 512 FMAs.
__global__ __launch_bounds__(256) void vq_main(const float* __restrict__ in,
                                               const float* __restrict__ emb,
                                               const float* __restrict__ se,
                                               float* __restrict__ out,
                                               double* __restrict__ loss_sum,
                                               int* __restrict__ counts) {
    __shared__ float xs[PIXB][XPAD];    // 17408 B
    __shared__ float sb[SPLIT][PIXB];
    __shared__ int   sk[SPLIT][PIXB];
    __shared__ int   skfin[PIXB];

    const int tid   = threadIdx.x;
    const int lane  = tid & 63;
    const int split = tid >> 6;
    const int n0    = blockIdx.x * PIXB;
    const int n     = n0 + lane;
    const int b     = n0 >> 12;         // batch (constant per block: 4096%64==0)
    const int s0    = n0 & 4095;

    // stage with transpose: global [d][pixel] (coalesced reads) -> xs[pixel][d]
    {
        const float* base = in + ((size_t)b << 18) + s0;
        #pragma unroll
        for (int i = 0; i < 16; ++i) {
            int d = split + (i << 2);
            xs[lane][d] = base[((size_t)d << 12) + lane];
        }
    }
    __syncthreads();

    // s_x exactly as numpy's pairwise_sum(flat*flat): r[j] += x[8i+j]^2 in
    // ascending i, via ordered quad loads from own row.
    float sx;
    {
        float r[8];
        {
            float4 q0 = *(const float4*)&xs[lane][0];
            float4 q1 = *(const float4*)&xs[lane][4];
            r[0] = __fmul_rn(q0.x, q0.x); r[1] = __fmul_rn(q0.y, q0.y);
            r[2] = __fmul_rn(q0.z, q0.z); r[3] = __fmul_rn(q0.w, q0.w);
            r[4] = __fmul_rn(q1.x, q1.x); r[5] = __fmul_rn(q1.y, q1.y);
            r[6] = __fmul_rn(q1.z, q1.z); r[7] = __fmul_rn(q1.w, q1.w);
        }
        #pragma unroll
        for (int i = 8; i < D; i += 8) {
            float4 q0 = *(const float4*)&xs[lane][i];
            float4 q1 = *(const float4*)&xs[lane][i + 4];
            r[0] = __fadd_rn(r[0], __fmul_rn(q0.x, q0.x));
            r[1] = __fadd_rn(r[1], __fmul_rn(q0.y, q0.y));
            r[2] = __fadd_rn(r[2], __fmul_rn(q0.z, q0.z));
            r[3] = __fadd_rn(r[3], __fmul_rn(q0.w, q0.w));
            r[4] = __fadd_rn(r[4], __fmul_rn(q1.x, q1.x));
            r[5] = __fadd_rn(r[5], __fmul_rn(q1.y, q1.y));
            r[6] = __fadd_rn(r[6], __fmul_rn(q1.z, q1.z));
            r[7] = __fadd_rn(r[7], __fmul_rn(q1.w, q1.w));
        }
        float X = __fadd_rn(__fadd_rn(r[0], r[1]), __fadd_rn(r[2], r[3]));
        float Y = __fadd_rn(__fadd_rn(r[4], r[5]), __fadd_rn(r[6], r[7]));
        sx = __fadd_rn(X, Y);
    }

    // wave-uniform codebook chunk base -> scalar (s_load) codebook reads
    const int kbase = __builtin_amdgcn_readfirstlane(split * KCHUNK);
    const float* eb = emb + (size_t)kbase * D;
    const float* hb = se + kbase;

    float best = 3.0e38f;
    int bestk  = 0x7fffffff;
    int xrow   = lane;

    for (int k = 0; k < KCHUNK; k += 8) {
        // redefine xrow each iteration so LICM cannot hoist the 16 b128 reads
        // out of the k-loop (would demand 64 live VGPRs -> remat/spill mess)
        asm volatile("" : "+v"(xrow));
        float a[8];
        #pragma unroll
        for (int c = 0; c < 8; ++c) a[c] = 0.f;
        #pragma unroll
        for (int dq = 0; dq < 16; ++dq) {
            float4 xq = *(const float4*)&xs[xrow][dq << 2];
            #pragma unroll
            for (int c = 0; c < 8; ++c) {
                const float* e = eb + (size_t)(k + c) * D + (dq << 2);
                // single sequential fmaf chain per code, d ascending (sgemm)
                a[c] = fmaf(xq.x, e[0], a[c]);
                a[c] = fmaf(xq.y, e[1], a[c]);
                a[c] = fmaf(xq.z, e[2], a[c]);
                a[c] = fmaf(xq.w, e[3], a[c]);
            }
        }
        #pragma unroll
        for (int c = 0; c < 8; ++c) {
            // numpy: fl( fl(sx + se_k) - 2*m_k )
            float sv = __fsub_rn(__fadd_rn(sx, hb[k + c]), __fmul_rn(2.0f, a[c]));
            // strict < in ascending k == np.argmin first-min semantics
            if (sv < best) { best = sv; bestk = kbase + k + c; }
        }
    }

    sb[split][lane] = best;
    sk[split][lane] = bestk;
    __syncthreads();

    if (split == 0) {
        // ascending split order + strict < preserves np.argmin first-min
        #pragma unroll
        for (int j = 1; j < SPLIT; ++j) {
            float bj = sb[j][lane];
            int   kj = sk[j][lane];
            if (bj < best) { best = bj; bestk = kj; }
        }
        skfin[lane] = bestk;
        atomicAdd(&counts[bestk], 1);
        out[IDX_OFF + (unsigned)n] = (float)bestk;

        // quantized (NCHW) + per-pixel squared error
        const float* eq = emb + (size_t)bestk * D;
        float* qout = out + QUANT_OFF + ((size_t)b << 18) + s0 + lane;
        float mse = 0.f;
        #pragma unroll
        for (int d = 0; d < D; ++d) {
            float q = eq[d];
            qout[(size_t)d << 12] = q;
            float df = q - xs[lane][d];
            mse = fmaf(df, df, mse);
        }
        #pragma unroll
        for (int off = 32; off; off >>= 1) mse += __shfl_down(mse, off);
        if (lane == 0) atomicAdd(loss_sum, (double)mse);
    }
    __syncthreads();

    // one-hot encodings rows for this block's 64 pixels (256 KB).
    // Region starts at ENC_OFF + n0*1024 (global float idx == 2 mod 4), so
    // shift by 2 floats for aligned float4 stores; head/tail as float2.
    float4* dst4 = (float4*)(out + ENC_OFF + (size_t)n0 * KCODES + 2);
    for (int i = tid; i < 16383; i += BLOCK) {
        int flat = (i << 2) + 2;          // 2 .. 65530
        int r0 = flat >> 10;
        int r1 = (flat + 3) >> 10;        // row crossing only at c==1022
        int k0 = skfin[r0];
        int k1 = skfin[r1];
        int c  = flat & 1023;             // in {2,6,...,1022}
        float4 v;
        v.x = (c == k0) ? 1.f : 0.f;
        v.y = (c + 1 == k0) ? 1.f : 0.f;
        v.z = (((flat + 2) & 1023) == k1) ? 1.f : 0.f;
        v.w = (((flat + 3) & 1023) == k1) ? 1.f : 0.f;
        dst4[i] = v;
    }
    if (tid == 0) {
        float2* dh = (float2*)(out + ENC_OFF + (size_t)n0 * KCODES);
        int kh = skfin[0];
        float2 h2; h2.x = (kh == 0) ? 1.f : 0.f; h2.y = (kh == 1) ? 1.f : 0.f;
        *dh = h2;
        float2* dt = (float2*)(out + ENC_OFF + (size_t)n0 * KCODES + 65534);
        int kt = skfin[63];
        float2 t2; t2.x = (kt == 1022) ? 1.f : 0.f; t2.y = (kt == 1023) ? 1.f : 0.f;
        *dt = t2;
    }
}

__global__ __launch_bounds__(256) void vq_fin(const double* __restrict__ loss_sum,
                                              const int* __restrict__ counts,
                                              float* __restrict__ out) {
    __shared__ double red[256];
    int t = threadIdx.x;
    double ent = 0.0;
    for (int k = t; k < KCODES; k += 256) {
        double p = (double)counts[k] / 65536.0;
        ent -= p * log(p + 1e-10);
    }
    red[t] = ent;
    __syncthreads();
    for (int o = 128; o; o >>= 1) {
        if (t < o) red[t] += red[t + o];
        __syncthreads();
    }
    if (t == 0) {
        out[PERP_OFF] = (float)exp(red[0]);
        out[0] = (float)(1.25 * (*loss_sum) / 4194304.0);
    }
}

extern "C" void kernel_launch(void* const* d_in, const int* in_sizes, int n_in,
                              void* d_out, int out_size, void* d_ws, size_t ws_size,
                              hipStream_t stream) {
    const float* in  = (const float*)d_in[0];
    const float* emb = (const float*)d_in[1];
    float* out = (float*)d_out;

    double* loss_sum = (double*)d_ws;
    int*    counts   = (int*)((char*)d_ws + 8);
    float*  se       = (float*)((char*)d_ws + 8 + 4096);

    vq_init<<<4, 256, 0, stream>>>(emb, loss_sum, counts, se);
    vq_main<<<NPIX / PIXB, BLOCK, 0, stream>>>(in, emb, se, out, loss_sum, counts);
    vq_fin<<<1, 256, 0, stream>>>(loss_sum, counts, out);
}

// Round 8
// 183.273 us; speedup vs baseline: 1.1680x; 1.1082x over previous
//
#include <hip/hip_runtime.h>

#define NPIX    65536
#define D       64
#define KCODES  1024
#define SPLIT   8
#define KCHUNK  (KCODES / SPLIT)   // 128
#define PIXB    64
#define BLOCK   512
#define XPAD    68                 // row stride in floats

// d_out layout (floats):
//   [0]                  loss
//   [1 .. 4194305)       quantized_out (NCHW, 16x64x64x64)
//   [4194305]            perplexity
//   [4194306 .. 71303170) encodings (65536 x 1024)
//   [71303170 .. 71368706) indices (as float)
#define QUANT_OFF 1
#define PERP_OFF  4194305
#define ENC_OFF   4194306u
#define IDX_OFF   71303170u

// numpy pairwise_sum (8 <= n <= 128) for n=64: 8 accumulators over stride-8
// lanes, sequential adds, then ((r0+r1)+(r2+r3))+((r4+r5)+(r6+r7)).
// All ops via __fmul_rn/__fadd_rn so the compiler cannot contract or reorder.

__global__ __launch_bounds__(256) void vq_init(const float* __restrict__ emb,
                                               double* __restrict__ loss_sum,
                                               int* __restrict__ counts,
                                               float* __restrict__ se) {
    int t = blockIdx.x * 256 + threadIdx.x;
    if (t == 0) *loss_sum = 0.0;
    if (t < KCODES) {
        counts[t] = 0;
        const float* e = emb + (size_t)t * D;
        float r[8];
        #pragma unroll
        for (int j = 0; j < 8; ++j) r[j] = __fmul_rn(e[j], e[j]);
        #pragma unroll
        for (int i = 8; i < D; i += 8)
            #pragma unroll
            for (int j = 0; j < 8; ++j)
                r[j] = __fadd_rn(r[j], __fmul_rn(e[i + j], e[i + j]));
        float X = __fadd_rn(__fadd_rn(r[0], r[1]), __fadd_rn(r[2], r[3]));
        float Y = __fadd_rn(__fadd_rn(r[4], r[5]), __fadd_rn(r[6], r[7]));
        se[t] = __fadd_rn(X, Y);
    }
}

// Rounds 3-7 post-mortem: dur ~210-240 us invariant across x-path structures,
// VALUBusy 59-65% -> latency-bound at 4 waves/SIMD (allocator caps VGPR at
// ~36-56, no deep prefetch possible). Fix: SPLIT=8, 512-thread blocks, same
// 1024-block grid -> 32 waves/CU (100% occupancy) to fill the wait gaps.
__global__ __launch_bounds__(512) void vq_main(const float* __restrict__ in,
                                               const float* __restrict__ emb,
                                               const float* __restrict__ se,
                                               float* __restrict__ out,
                                               double* __restrict__ loss_sum,
                                               int* __restrict__ counts) {
    __shared__ float xs[PIXB][XPAD];    // 17408 B
    __shared__ float sb[SPLIT][PIXB];
    __shared__ int   sk[SPLIT][PIXB];
    __shared__ int   skfin[PIXB];

    const int tid   = threadIdx.x;
    const int lane  = tid & 63;
    const int split = tid >> 6;         // 0..7
    const int n0    = blockIdx.x * PIXB;
    const int n     = n0 + lane;
    const int b     = n0 >> 12;         // batch (constant per block: 4096%64==0)
    const int s0    = n0 & 4095;

    // stage with transpose: global [d][pixel] (coalesced reads) -> xs[pixel][d]
    {
        const float* base = in + ((size_t)b << 18) + s0;
        #pragma unroll
        for (int i = 0; i < 8; ++i) {
            int d = split + (i << 3);
            xs[lane][d] = base[((size_t)d << 12) + lane];
        }
    }
    __syncthreads();

    // s_x exactly as numpy's pairwise_sum(flat*flat): r[j] += x[8i+j]^2 in
    // ascending i, via ordered quad loads from own row.
    float sx;
    {
        float r[8];
        {
            float4 q0 = *(const float4*)&xs[lane][0];
            float4 q1 = *(const float4*)&xs[lane][4];
            r[0] = __fmul_rn(q0.x, q0.x); r[1] = __fmul_rn(q0.y, q0.y);
            r[2] = __fmul_rn(q0.z, q0.z); r[3] = __fmul_rn(q0.w, q0.w);
            r[4] = __fmul_rn(q1.x, q1.x); r[5] = __fmul_rn(q1.y, q1.y);
            r[6] = __fmul_rn(q1.z, q1.z); r[7] = __fmul_rn(q1.w, q1.w);
        }
        #pragma unroll
        for (int i = 8; i < D; i += 8) {
            float4 q0 = *(const float4*)&xs[lane][i];
            float4 q1 = *(const float4*)&xs[lane][i + 4];
            r[0] = __fadd_rn(r[0], __fmul_rn(q0.x, q0.x));
            r[1] = __fadd_rn(r[1], __fmul_rn(q0.y, q0.y));
            r[2] = __fadd_rn(r[2], __fmul_rn(q0.z, q0.z));
            r[3] = __fadd_rn(r[3], __fmul_rn(q0.w, q0.w));
            r[4] = __fadd_rn(r[4], __fmul_rn(q1.x, q1.x));
            r[5] = __fadd_rn(r[5], __fmul_rn(q1.y, q1.y));
            r[6] = __fadd_rn(r[6], __fmul_rn(q1.z, q1.z));
            r[7] = __fadd_rn(r[7], __fmul_rn(q1.w, q1.w));
        }
        float X = __fadd_rn(__fadd_rn(r[0], r[1]), __fadd_rn(r[2], r[3]));
        float Y = __fadd_rn(__fadd_rn(r[4], r[5]), __fadd_rn(r[6], r[7]));
        sx = __fadd_rn(X, Y);
    }

    // wave-uniform codebook chunk base -> scalar (s_load) codebook reads
    const int kbase = __builtin_amdgcn_readfirstlane(split * KCHUNK);
    const float* eb = emb + (size_t)kbase * D;
    const float* hb = se + kbase;

    float best = 3.0e38f;
    int bestk  = 0x7fffffff;
    int xrow   = lane;

    for (int k = 0; k < KCHUNK; k += 8) {
        // redefine xrow each iteration so LICM cannot hoist the 16 b128 reads
        // out of the k-loop (would demand 64 live VGPRs -> remat/spill mess)
        asm volatile("" : "+v"(xrow));
        float a[8];
        #pragma unroll
        for (int c = 0; c < 8; ++c) a[c] = 0.f;
        float4 xq = *(const float4*)&xs[xrow][0];
        #pragma unroll
        for (int dq = 0; dq < 16; ++dq) {
            // 1-deep prefetch of the next d-quad hides LDS latency under FMAs
            float4 nxt = (dq < 15) ? *(const float4*)&xs[xrow][(dq + 1) << 2] : xq;
            #pragma unroll
            for (int c = 0; c < 8; ++c) {
                const float* e = eb + (size_t)(k + c) * D + (dq << 2);
                // single sequential fmaf chain per code, d ascending (sgemm)
                a[c] = fmaf(xq.x, e[0], a[c]);
                a[c] = fmaf(xq.y, e[1], a[c]);
                a[c] = fmaf(xq.z, e[2], a[c]);
                a[c] = fmaf(xq.w, e[3], a[c]);
            }
            xq = nxt;
        }
        #pragma unroll
        for (int c = 0; c < 8; ++c) {
            // numpy: fl( fl(sx + se_k) - 2*m_k )
            float sv = __fsub_rn(__fadd_rn(sx, hb[k + c]), __fmul_rn(2.0f, a[c]));
            // strict < in ascending k == np.argmin first-min semantics
            if (sv < best) { best = sv; bestk = kbase + k + c; }
        }
    }

    sb[split][lane] = best;
    sk[split][lane] = bestk;
    __syncthreads();

    if (split == 0) {
        // ascending split order + strict < preserves np.argmin first-min
        #pragma unroll
        for (int j = 1; j < SPLIT; ++j) {
            float bj = sb[j][lane];
            int   kj = sk[j][lane];
            if (bj < best) { best = bj; bestk = kj; }
        }
        skfin[lane] = bestk;
        atomicAdd(&counts[bestk], 1);
        out[IDX_OFF + (unsigned)n] = (float)bestk;

        // quantized (NCHW) + per-pixel squared error
        const float* eq = emb + (size_t)bestk * D;
        float* qout = out + QUANT_OFF + ((size_t)b << 18) + s0 + lane;
        float mse = 0.f;
        #pragma unroll
        for (int d = 0; d < D; ++d) {
            float q = eq[d];
            qout[(size_t)d << 12] = q;
            float df = q - xs[lane][d];
            mse = fmaf(df, df, mse);
        }
        #pragma unroll
        for (int off = 32; off; off >>= 1) mse += __shfl_down(mse, off);
        if (lane == 0) atomicAdd(loss_sum, (double)mse);
    }
    __syncthreads();

    // one-hot encodings rows for this block's 64 pixels (256 KB).
    // Region starts at ENC_OFF + n0*1024 (global float idx == 2 mod 4), so
    // shift by 2 floats for aligned float4 stores; head/tail as float2.
    float4* dst4 = (float4*)(out + ENC_OFF + (size_t)n0 * KCODES + 2);
    for (int i = tid; i < 16383; i += BLOCK) {
        int flat = (i << 2) + 2;          // 2 .. 65530
        int r0 = flat >> 10;
        int r1 = (flat + 3) >> 10;        // row crossing only at c==1022
        int k0 = skfin[r0];
        int k1 = skfin[r1];
        int c  = flat & 1023;             // in {2,6,...,1022}
        float4 v;
        v.x = (c == k0) ? 1.f : 0.f;
        v.y = (c + 1 == k0) ? 1.f : 0.f;
        v.z = (((flat + 2) & 1023) == k1) ? 1.f : 0.f;
        v.w = (((flat + 3) & 1023) == k1) ? 1.f : 0.f;
        dst4[i] = v;
    }
    if (tid == 0) {
        float2* dh = (float2*)(out + ENC_OFF + (size_t)n0 * KCODES);
        int kh = skfin[0];
        float2 h2; h2.x = (kh == 0) ? 1.f : 0.f; h2.y = (kh == 1) ? 1.f : 0.f;
        *dh = h2;
        float2* dt = (float2*)(out + ENC_OFF + (size_t)n0 * KCODES + 65534);
        int kt = skfin[63];
        float2 t2; t2.x = (kt == 1022) ? 1.f : 0.f; t2.y = (kt == 1023) ? 1.f : 0.f;
        *dt = t2;
    }
}

__global__ __launch_bounds__(256) void vq_fin(const double* __restrict__ loss_sum,
                                              const int* __restrict__ counts,
                                              float* __restrict__ out) {
    __shared__ double red[256];
    int t = threadIdx.x;
    double ent = 0.0;
    for (int k = t; k < KCODES; k += 256) {
        double p = (double)counts[k] / 65536.0;
        ent -= p * log(p + 1e-10);
    }
    red[t] = ent;
    __syncthreads();
    for (int o = 128; o; o >>= 1) {
        if (t < o) red[t] += red[t + o];
        __syncthreads();
    }
    if (t == 0) {
        out[PERP_OFF] = (float)exp(red[0]);
        out[0] = (float)(1.25 * (*loss_sum) / 4194304.0);
    }
}

extern "C" void kernel_launch(void* const* d_in, const int* in_sizes, int n_in,
                              void* d_out, int out_size, void* d_ws, size_t ws_size,
                              hipStream_t stream) {
    const float* in  = (const float*)d_in[0];
    const float* emb = (const float*)d_in[1];
    float* out = (float*)d_out;

    double* loss_sum = (double*)d_ws;
    int*    counts   = (int*)((char*)d_ws + 8);
    float*  se       = (float*)((char*)d_ws + 8 + 4096);

    vq_init<<<4, 256, 0, stream>>>(emb, loss_sum, counts, se);
    vq_main<<<NPIX / PIXB, BLOCK, 0, stream>>>(in, emb, se, out, loss_sum, counts);
    vq_fin<<<1, 256, 0, stream>>>(loss_sum, counts, out);
}